// Round 1
// 229.819 us; speedup vs baseline: 1.1817x; 1.1817x over previous
//
#include <hip/hip_runtime.h>

// Problem constants (fixed by reference setup_inputs)
#define B_    8
#define C_    16
#define T_    2000
#define F_    128
#define F4_   32           // F_/4
#define POOL_ 10
#define T1_   200          // T_/POOL_ (exact, no tail)
#define BC_   128          // B_*C_
#define EPS_  1e-5f

#define G_      8          // pooled blocks per chunk
#define NCHUNK_ 25         // T1_/G_
#define HF4_    16         // float4 per 64-feature half row

// ---------------------------------------------------------------------------
// Fully fused causal instance-norm. One WG per (bc, feature-half).
// Sequential sweep over T1 pooled blocks in chunks of G_=8:
//   - thread (g,k2,f4) loads 5 float4 rows of block t1=c*8+g (k = k2,k2+2..)
//   - fold k2 pair via shfl_xor(16) -> per-block sums s, s2
//   - publish to LDS, barrier, causal prefix over groups + running total
//   - normalize the registers just loaded, store out (same addresses)
// x read once (131 MB), out written once (131 MB). Next chunk prefetched
// before the barrier so HBM latency hides under LDS/stats/store phase.
// ---------------------------------------------------------------------------
__global__ __launch_bounds__(256) void fused_cumnorm(
    const float4* __restrict__ x4, float4* __restrict__ out4)
{
    const int tid  = (int)threadIdx.x;
    const int bc   = (int)blockIdx.x >> 1;
    const int half = (int)blockIdx.x & 1;
    const int g    = tid >> 5;          // 0..7  : pooled block within chunk
    const int k2   = (tid >> 4) & 1;    // 0..1  : row parity within block
    const int f4   = tid & 15;          // 0..15 : float4 column within half

    __shared__ float4 sS  [G_][HF4_];   // per-chunk block sums
    __shared__ float4 sS2 [G_][HF4_];
    __shared__ float4 runS [2][HF4_];   // running totals, parity double-buffer
    __shared__ float4 runS2[2][HF4_];

    const size_t tbase = (size_t)bc * T_ * F4_ + (size_t)half * HF4_ + (size_t)f4
                       + (size_t)(g * POOL_ + k2) * F4_;
    const float4* __restrict__ pc = x4   + tbase;
    float4*       __restrict__ qc = out4 + tbase;

    const int RS = 2 * F4_;             // 64  : row-pair stride (same-parity rows)
    const int CS = G_ * POOL_ * F4_;    // 2560: chunk stride

    // prologue: load chunk 0
    float4 v0 = pc[0], v1 = pc[RS], v2 = pc[2*RS], v3 = pc[3*RS], v4 = pc[4*RS];

    if (tid < HF4_) {
        runS [0][tid] = make_float4(0.f, 0.f, 0.f, 0.f);
        runS2[0][tid] = make_float4(0.f, 0.f, 0.f, 0.f);
    }
    // (covered by the first in-loop __syncthreads before any read)

    for (int c = 0; c < NCHUNK_; ++c) {
        // ---- partial block sums over this thread's 5 rows
        float4 s, s2;
        s.x = ((v0.x + v1.x) + (v2.x + v3.x)) + v4.x;
        s.y = ((v0.y + v1.y) + (v2.y + v3.y)) + v4.y;
        s.z = ((v0.z + v1.z) + (v2.z + v3.z)) + v4.z;
        s.w = ((v0.w + v1.w) + (v2.w + v3.w)) + v4.w;
        s2.x = v0.x*v0.x; s2.x = fmaf(v1.x,v1.x,s2.x); s2.x = fmaf(v2.x,v2.x,s2.x); s2.x = fmaf(v3.x,v3.x,s2.x); s2.x = fmaf(v4.x,v4.x,s2.x);
        s2.y = v0.y*v0.y; s2.y = fmaf(v1.y,v1.y,s2.y); s2.y = fmaf(v2.y,v2.y,s2.y); s2.y = fmaf(v3.y,v3.y,s2.y); s2.y = fmaf(v4.y,v4.y,s2.y);
        s2.z = v0.z*v0.z; s2.z = fmaf(v1.z,v1.z,s2.z); s2.z = fmaf(v2.z,v2.z,s2.z); s2.z = fmaf(v3.z,v3.z,s2.z); s2.z = fmaf(v4.z,v4.z,s2.z);
        s2.w = v0.w*v0.w; s2.w = fmaf(v1.w,v1.w,s2.w); s2.w = fmaf(v2.w,v2.w,s2.w); s2.w = fmaf(v3.w,v3.w,s2.w); s2.w = fmaf(v4.w,v4.w,s2.w);

        // ---- fold the k2 pair (lanes l <-> l^16 within each 32-lane group)
        s.x  += __shfl_xor(s.x , 16);
        s.y  += __shfl_xor(s.y , 16);
        s.z  += __shfl_xor(s.z , 16);
        s.w  += __shfl_xor(s.w , 16);
        s2.x += __shfl_xor(s2.x, 16);
        s2.y += __shfl_xor(s2.y, 16);
        s2.z += __shfl_xor(s2.z, 16);
        s2.w += __shfl_xor(s2.w, 16);

        // ---- issue next chunk's loads early (hide HBM under LDS/stats/store)
        float4 w0, w1, w2, w3, w4;
        if (c + 1 < NCHUNK_) {
            const float4* pn = pc + CS;
            w0 = pn[0]; w1 = pn[RS]; w2 = pn[2*RS]; w3 = pn[3*RS]; w4 = pn[4*RS];
        } else {
            w0 = v0; w1 = v1; w2 = v2; w3 = v3; w4 = v4;
        }

        if (k2 == 0) { sS[g][f4] = s; sS2[g][f4] = s2; }
        __syncthreads();

        // ---- causal inclusive prefix over groups, seeded by running total
        float4 acc  = runS [c & 1][f4];
        float4 acc2 = runS2[c & 1][f4];
#pragma unroll
        for (int j = 0; j < G_; ++j) {
            float4 aj  = sS [j][f4];
            float4 a2j = sS2[j][f4];
            if (j <= g) {
                acc.x  += aj.x;  acc.y  += aj.y;  acc.z  += aj.z;  acc.w  += aj.w;
                acc2.x += a2j.x; acc2.y += a2j.y; acc2.z += a2j.z; acc2.w += a2j.w;
            }
        }

        const float inv = 1.0f / (float)((c * G_ + g + 1) * POOL_);
        float4 mean, rstd;
        mean.x = acc.x * inv; rstd.x = rsqrtf(fmaf(-mean.x, mean.x, acc2.x * inv) + EPS_);
        mean.y = acc.y * inv; rstd.y = rsqrtf(fmaf(-mean.y, mean.y, acc2.y * inv) + EPS_);
        mean.z = acc.z * inv; rstd.z = rsqrtf(fmaf(-mean.z, mean.z, acc2.z * inv) + EPS_);
        mean.w = acc.w * inv; rstd.w = rsqrtf(fmaf(-mean.w, mean.w, acc2.w * inv) + EPS_);

        // ---- normalize held registers, store (same addresses as loads)
        float4 o;
        o.x = (v0.x - mean.x) * rstd.x; o.y = (v0.y - mean.y) * rstd.y;
        o.z = (v0.z - mean.z) * rstd.z; o.w = (v0.w - mean.w) * rstd.w;
        qc[0] = o;
        o.x = (v1.x - mean.x) * rstd.x; o.y = (v1.y - mean.y) * rstd.y;
        o.z = (v1.z - mean.z) * rstd.z; o.w = (v1.w - mean.w) * rstd.w;
        qc[RS] = o;
        o.x = (v2.x - mean.x) * rstd.x; o.y = (v2.y - mean.y) * rstd.y;
        o.z = (v2.z - mean.z) * rstd.z; o.w = (v2.w - mean.w) * rstd.w;
        qc[2*RS] = o;
        o.x = (v3.x - mean.x) * rstd.x; o.y = (v3.y - mean.y) * rstd.y;
        o.z = (v3.z - mean.z) * rstd.z; o.w = (v3.w - mean.w) * rstd.w;
        qc[3*RS] = o;
        o.x = (v4.x - mean.x) * rstd.x; o.y = (v4.y - mean.y) * rstd.y;
        o.z = (v4.z - mean.z) * rstd.z; o.w = (v4.w - mean.w) * rstd.w;
        qc[4*RS] = o;

        // ---- group 7's prefix IS the new running total (double-buffered)
        if (g == G_ - 1 && k2 == 0) {
            runS [(c + 1) & 1][f4] = acc;
            runS2[(c + 1) & 1][f4] = acc2;
        }
        __syncthreads();   // protects sS/sS2 overwrite + runS publish

        v0 = w0; v1 = w1; v2 = w2; v3 = w3; v4 = w4;
        pc += CS; qc += CS;
    }
}

extern "C" void kernel_launch(void* const* d_in, const int* in_sizes, int n_in,
                              void* d_out, int out_size, void* d_ws, size_t ws_size,
                              hipStream_t stream)
{
    (void)in_sizes; (void)n_in; (void)d_ws; (void)ws_size; (void)out_size;
    // 128 bc x 2 feature-halves = 256 WGs (1/CU), 256 threads (4 waves)
    fused_cumnorm<<<BC_ * 2, 256, 0, stream>>>(
        (const float4*)d_in[0], (float4*)d_out);
}